// Round 6
// baseline (1616.746 us; speedup 1.0000x reference)
//
#include <hip/hip_runtime.h>
#include <hip/hip_bf16.h>

// Problem constants
#define B_  64
#define T_  512
#define E_  256
#define H_  512
#define G4_ 2048
#define C_  4

typedef __attribute__((ext_vector_type(4))) float  f32x4;
typedef __attribute__((ext_vector_type(8))) __bf16 bf16x8;
typedef __attribute__((ext_vector_type(8))) short  short8;   // no HIP builtin 'short8'
typedef __attribute__((ext_vector_type(4))) short  s16x4;    // HIP predefines 'short4'
typedef __attribute__((ext_vector_type(4))) unsigned int u32x4;
typedef __attribute__((ext_vector_type(2))) unsigned int u32x2;

union V16 { f32x4 f; bf16x8 b; short8 s; };

__device__ __forceinline__ float sigmoid_(float x) { return 1.0f / (1.0f + __expf(-x)); }
__device__ __forceinline__ float tanh_(float x)    { return 1.0f - 2.0f / (__expf(2.0f * x) + 1.0f); }

// Deterministic RNE fp32 -> bf16
__device__ __forceinline__ short f2bf(float f) {
  union { float f; unsigned u; } v; v.f = f;
  return (short)((v.u + 0x7FFFu + ((v.u >> 16) & 1u)) >> 16);
}

// --- per-access LLC-coherent ops (sc0 sc1 = bypass L1+L2, coherent point) ---
__device__ __forceinline__ void store_u32_llc(void* p, unsigned v) {
  asm volatile("global_store_dword %0, %1, off sc0 sc1" :: "v"(p), "v"(v) : "memory");
}
__device__ __forceinline__ void store_f32_llc(void* p, float v) {
  asm volatile("global_store_dword %0, %1, off sc0 sc1" :: "v"(p), "v"(v) : "memory");
}
// four pipelined coherent 16B loads + single drain (the poll/stage load)
__device__ __forceinline__ void load4x16_llc(const void* q0, const void* q1,
                                             const void* q2, const void* q3,
                                             u32x4* a, u32x4* b, u32x4* c, u32x4* d) {
  asm volatile(
      "global_load_dwordx4 %0, %4, off sc0 sc1\n\t"
      "global_load_dwordx4 %1, %5, off sc0 sc1\n\t"
      "global_load_dwordx4 %2, %6, off sc0 sc1\n\t"
      "global_load_dwordx4 %3, %7, off sc0 sc1\n\t"
      "s_waitcnt vmcnt(0)"
      : "=&v"(*a), "=&v"(*b), "=&v"(*c), "=&v"(*d)
      : "v"(q0), "v"(q1), "v"(q2), "v"(q3)
      : "memory");
}

// ---------------------------------------------------------------------------
// Phase 1: xg[t][g][b][d] = (emb[x[b][t]] @ W_ih^T)[g*512+d]  (bias added later)
// Same MFMA structure as rounds 3-5 (proven); C-writes now packed 4x bf16
// (8B dwordx2) instead of scalar 2B stores -> 4x fewer store ops.
// ---------------------------------------------------------------------------
__global__ __launch_bounds__(256, 1) void xg_kernel(
    const int* __restrict__ x, const float* __restrict__ emb,
    const float* __restrict__ W_ih,
    __hip_bfloat16* __restrict__ xg)
{
  const int t   = blockIdx.x;
  const int tid = threadIdx.x;
  __shared__ int s_idx[B_];
  __shared__ __hip_bfloat16 s_e[B_][E_ + 8];

  if (tid < B_) s_idx[tid] = x[tid * T_ + t];
  __syncthreads();
  {
    int b = tid >> 2, ch = tid & 3;
    const float* src = emb + (size_t)s_idx[b] * E_ + ch * 64;
    short* dst = (short*)&s_e[b][ch * 64];
#pragma unroll
    for (int i = 0; i < 16; i++) {
      f32x4 v = *(const f32x4*)(src + i * 4);
      s16x4 s;
      s[0] = f2bf(v[0]); s[1] = f2bf(v[1]); s[2] = f2bf(v[2]); s[3] = f2bf(v[3]);
      *(s16x4*)(dst + i * 4) = s;
    }
  }
  __syncthreads();

  const int wv   = tid >> 6;
  const int lane = tid & 63;
  const int ln15 = lane & 15, quad = lane >> 4;

  V16 breg[4][8];
#pragma unroll
  for (int nt = 0; nt < 4; nt++)
#pragma unroll
    for (int ks = 0; ks < 8; ks++)
      breg[nt][ks].f = *(const f32x4*)(&s_e[nt * 16 + ln15][quad * 8 + ks * 32]);

  const int gbase = wv * 512;
  const size_t base_t = (size_t)t * (G4_ * B_);
  for (int mt = 0; mt < 32; mt++) {
    const int grow = gbase + mt * 16 + ln15;
    const float* arow = W_ih + (size_t)grow * E_ + quad * 8;
    V16 areg[8];
#pragma unroll
    for (int ks = 0; ks < 8; ks++) {
      f32x4 lo = *(const f32x4*)(arow + ks * 32);
      f32x4 hi = *(const f32x4*)(arow + ks * 32 + 4);
      short8 s;
      s[0] = f2bf(lo[0]); s[1] = f2bf(lo[1]); s[2] = f2bf(lo[2]); s[3] = f2bf(lo[3]);
      s[4] = f2bf(hi[0]); s[5] = f2bf(hi[1]); s[6] = f2bf(hi[2]); s[7] = f2bf(hi[3]);
      areg[ks].s = s;
    }

    f32x4 acc[4];
#pragma unroll
    for (int nt = 0; nt < 4; nt++) acc[nt] = (f32x4){0.f, 0.f, 0.f, 0.f};
#pragma unroll
    for (int ks = 0; ks < 8; ks++)
#pragma unroll
      for (int nt = 0; nt < 4; nt++)
        acc[nt] = __builtin_amdgcn_mfma_f32_16x16x32_bf16(areg[ks].b, breg[nt][ks].b, acc[nt], 0, 0, 0);

    // C layout: col = batch (lane&15), rows m = quad*4 + r -> 4 consecutive d
    const int dbase = mt * 16 + quad * 4;    // gbase&511 == 0
#pragma unroll
    for (int nt = 0; nt < 4; nt++) {
      const int batch = nt * 16 + ln15;
      s16x4 sv;
#pragma unroll
      for (int r = 0; r < 4; r++) sv[r] = f2bf(acc[nt][r]);
      *(s16x4*)((short*)xg + base_t + ((size_t)wv << 15) + ((size_t)batch << 9) + dbase) = sv;
    }
  }
}

// ---------------------------------------------------------------------------
// Phase 2: persistent recurrent kernel, 64 blocks x 512 threads (8 waves).
// Block (pb = blk&3, pd = blk>>2): batches [pb*16,+16), h-dims [pd*32,+32).
// DATA-EMBEDDED SYNC: hbuf2 words = (bf16(h)<<16) | step_tag. Producers just
// store their tagged word (no drain, no flag, no trailing barrier). Consumers
// poll-load the data itself (4 coherent dwordx4/thread over the group's 32 KB)
// until all 16 tags == t, then unpack into LDS. Double buffer (parity t&1)
// makes tag==t race-free: a producer can only run 1 step ahead of any consumer
// of its group (its step-t+1 staging needs every peer's h_{t+1}, which is
// written only after that peer finished staging h_t). 2 barriers/step.
// ---------------------------------------------------------------------------
__global__ __launch_bounds__(512, 2) void lstm_kernel(
    const float* __restrict__ W_hh,
    const float* __restrict__ b_ih, const float* __restrict__ b_hh,
    const float* __restrict__ W_fc, const float* __restrict__ b_fc,
    const __hip_bfloat16* __restrict__ xg,
    unsigned int* flags, unsigned int* hbuf2 /*[2][64][512] tagged*/, float* hT,
    float* out)
{
  const int tid  = threadIdx.x;
  const int blk  = blockIdx.x;
  const int pb   = blk & 3;        // batch group
  const int pd   = blk >> 2;       // dim slice [pd*32, +32)
  const int d0   = pd * 32;
  const int wv   = tid >> 6;       // 0..7
  const int lane = tid & 63;
  const int ln15 = lane & 15, quad = lane >> 4;

  __shared__ __hip_bfloat16 s_h[16][520];      // h_t for our 16 batches (+8 pad)
  __shared__ float s_pre[4][16][36];           // [gate][batch][dim(+4 pad)]

  // Register-resident bf16 A fragments from fp32 W_hh.
  // Wave wv: gate g = wv>>1, local dims (wv&1)*16 + ln15.
  V16 areg[16];
  {
    const int grow = (wv >> 1) * 512 + d0 + (wv & 1) * 16 + ln15;
    const float* ap = W_hh + (size_t)grow * H_ + quad * 8;
#pragma unroll
    for (int ks = 0; ks < 16; ks++) {
      f32x4 lo = *(const f32x4*)(ap + ks * 32);
      f32x4 hi = *(const f32x4*)(ap + ks * 32 + 4);
      short8 s;
      s[0] = f2bf(lo[0]); s[1] = f2bf(lo[1]); s[2] = f2bf(lo[2]); s[3] = f2bf(lo[3]);
      s[4] = f2bf(hi[0]); s[5] = f2bf(hi[1]); s[6] = f2bf(hi[2]); s[7] = f2bf(hi[3]);
      areg[ks].s = s;
    }
  }

  // Gate-math mapping: one cell per thread (16 batches x 32 dims = 512)
  const int nb = tid >> 5;         // 0..15
  const int nd = tid & 31;         // 0..31
  const int gb = pb * 16 + nb;     // global batch
  const int dg = d0 + nd;          // global h-dim
  const float bias_i = b_ih[dg]        + b_hh[dg];
  const float bias_f = b_ih[512 + dg]  + b_hh[512 + dg];
  const float bias_g = b_ih[1024 + dg] + b_hh[1024 + dg];
  const float bias_o = b_ih[1536 + dg] + b_hh[1536 + dg];
  float c = 0.0f;

  // Staging geometry: group region = 8192 words; thread's pass-i load covers
  // words i*2048 + tid*4 .. +3 -> LDS row i*4 + (tid>>7), col (tid*4)&511.
  const int srow = tid >> 7;
  const int scol = (tid * 4) & 511;

  for (int t = 0; t < T_; t++) {
    const int cur = t & 1;

    // xg prefetch (plain cached loads; independent of h)
    const size_t xoff = (size_t)t * (G4_ * B_) + ((size_t)gb << 9) + dg;
    const __hip_bfloat16 xgi = xg[xoff];
    const __hip_bfloat16 xgf = xg[xoff + (1u << 15)];
    const __hip_bfloat16 xgg = xg[xoff + (2u << 15)];
    const __hip_bfloat16 xgo = xg[xoff + (3u << 15)];

    // Poll-stage: load until every word of h_t we own carries tag t.
    const unsigned* wb = hbuf2 + (size_t)cur * (B_ * H_) +
                         (size_t)(pb * 16) * H_ + tid * 4;
    u32x4 a0, a1, a2, a3;
    {
      const unsigned tg = (unsigned)t;
      while (true) {
        load4x16_llc(wb, wb + 2048, wb + 4096, wb + 6144, &a0, &a1, &a2, &a3);
        unsigned m = (a0[0] ^ tg) | (a0[1] ^ tg) | (a0[2] ^ tg) | (a0[3] ^ tg)
                   | (a1[0] ^ tg) | (a1[1] ^ tg) | (a1[2] ^ tg) | (a1[3] ^ tg)
                   | (a2[0] ^ tg) | (a2[1] ^ tg) | (a2[2] ^ tg) | (a2[3] ^ tg)
                   | (a3[0] ^ tg) | (a3[1] ^ tg) | (a3[2] ^ tg) | (a3[3] ^ tg);
        if ((m & 0xFFFFu) == 0) break;   // high bits are bf16 payload
      }
    }
    // Unpack high-halves -> LDS (8B per pass, conflict-free: wave-contiguous)
    {
      u32x2 v;
      v[0] = (a0[0] >> 16) | (a0[1] & 0xFFFF0000u);
      v[1] = (a0[2] >> 16) | (a0[3] & 0xFFFF0000u);
      *(u32x2*)&s_h[srow][scol] = v;
      v[0] = (a1[0] >> 16) | (a1[1] & 0xFFFF0000u);
      v[1] = (a1[2] >> 16) | (a1[3] & 0xFFFF0000u);
      *(u32x2*)&s_h[srow + 4][scol] = v;
      v[0] = (a2[0] >> 16) | (a2[1] & 0xFFFF0000u);
      v[1] = (a2[2] >> 16) | (a2[3] & 0xFFFF0000u);
      *(u32x2*)&s_h[srow + 8][scol] = v;
      v[0] = (a3[0] >> 16) | (a3[1] & 0xFFFF0000u);
      v[1] = (a3[2] >> 16) | (a3[3] & 0xFFFF0000u);
      *(u32x2*)&s_h[srow + 12][scol] = v;
    }
    __syncthreads();   // S2: staging complete (also fences prev-step s_pre reads)

    // B fragments from LDS; 16 MFMAs on 2 accumulator chains.
    f32x4 acc0 = (f32x4){0.f, 0.f, 0.f, 0.f};
    f32x4 acc1 = (f32x4){0.f, 0.f, 0.f, 0.f};
#pragma unroll
    for (int ks = 0; ks < 16; ks += 2) {
      V16 b0, b1;
      b0.f = *(const f32x4*)&s_h[ln15][quad * 8 + ks * 32];
      b1.f = *(const f32x4*)&s_h[ln15][quad * 8 + (ks + 1) * 32];
      acc0 = __builtin_amdgcn_mfma_f32_16x16x32_bf16(areg[ks].b,     b0.b, acc0, 0, 0, 0);
      acc1 = __builtin_amdgcn_mfma_f32_16x16x32_bf16(areg[ks + 1].b, b1.b, acc1, 0, 0, 0);
    }
    const f32x4 accs = acc0 + acc1;

    // Scatter: C row m=quad*4+r -> d_local=(wv&1)*16+quad*4+r
    *(f32x4*)&s_pre[wv >> 1][ln15][(wv & 1) * 16 + quad * 4] = accs;
    __syncthreads();   // S3: preactivations complete (also fences s_h MFMA reads)

    {
      const float pi = s_pre[0][nb][nd] + bias_i + __bfloat162float(xgi);
      const float pf = s_pre[1][nb][nd] + bias_f + __bfloat162float(xgf);
      const float pg = s_pre[2][nb][nd] + bias_g + __bfloat162float(xgg);
      const float po = s_pre[3][nb][nd] + bias_o + __bfloat162float(xgo);
      const float i_ = sigmoid_(pi), f_ = sigmoid_(pf);
      const float g_ = tanh_(pg),    o_ = sigmoid_(po);
      c = f_ * c + i_ * g_;
      const float h = o_ * tanh_(c);
      if (t < T_ - 1) {
        const unsigned w = ((unsigned)(unsigned short)f2bf(h) << 16) | (unsigned)(t + 1);
        store_u32_llc(hbuf2 + (size_t)(cur ^ 1) * (B_ * H_) + (size_t)gb * H_ + dg, w);
      } else {
        store_f32_llc(hT + gb * H_ + dg, h);
      }
    }
    // no trailing barrier: the tagged store IS the publication
  }

  // Final handshake for the FC: drain hT stores, then per-block flag.
  asm volatile("s_waitcnt vmcnt(0)" ::: "memory");
  __syncthreads();
  if (tid == 0)
    __hip_atomic_store(&flags[blk], (unsigned)T_,
                       __ATOMIC_RELAXED, __HIP_MEMORY_SCOPE_AGENT);

  // Phase 3: fp32 FC by block 0
  if (blk == 0) {
    if (tid < 64)
      while (__hip_atomic_load(&flags[tid], __ATOMIC_RELAXED, __HIP_MEMORY_SCOPE_AGENT) < (unsigned)T_) {}
    __builtin_amdgcn_fence(__ATOMIC_ACQUIRE, "agent");
    __syncthreads();
    for (int o = tid; o < B_ * C_; o += 512) {
      const int b = o >> 2, cl = o & 3;
      const f32x4* hr = (const f32x4*)(hT + b * H_);
      const f32x4* wr = (const f32x4*)(W_fc + cl * H_);
      float s = 0.f;
      for (int d4 = 0; d4 < H_ / 4; d4++) {
        const f32x4 hv = hr[d4];
        const f32x4 wv4 = wr[d4];
        s += hv[0] * wv4[0] + hv[1] * wv4[1] + hv[2] * wv4[2] + hv[3] * wv4[3];
      }
      s += b_fc[cl];
      out[o] = s;
    }
  }
}

// ---------------------------------------------------------------------------
// Workspace map (total 134,615,040 B < round-3-proven 134,742,016 floor):
//   [0, 1024)            : flags[64..256] (uint32, zeroed every launch)
//   [4096, 266240)       : hbuf2[2][64][512] u32 tagged (zeroed: h0=0, tag=0)
//   [266240, 397312)     : hT[64][512] fp32
//   [397312, 134615040)  : xg[T][4][B][512] bf16 (128 MiB)
// ---------------------------------------------------------------------------
extern "C" void kernel_launch(void* const* d_in, const int* in_sizes, int n_in,
                              void* d_out, int out_size, void* d_ws, size_t ws_size,
                              hipStream_t stream) {
  const int*   x    = (const int*)d_in[0];
  const float* emb  = (const float*)d_in[1];
  const float* W_ih = (const float*)d_in[2];
  const float* W_hh = (const float*)d_in[3];
  const float* b_ih = (const float*)d_in[4];
  const float* b_hh = (const float*)d_in[5];
  const float* W_fc = (const float*)d_in[6];
  const float* b_fc = (const float*)d_in[7];
  float* out = (float*)d_out;

  char* ws = (char*)d_ws;
  const size_t XG_OFF = 397312;
  const size_t NEEDED = XG_OFF + (size_t)T_ * G4_ * B_ * 2;
  if (ws_size < NEEDED) return;

  unsigned int*   flags = (unsigned int*)ws;
  unsigned int*   hbuf2 = (unsigned int*)(ws + 4096);
  float*          hT    = (float*)(ws + 266240);
  __hip_bfloat16* xg    = (__hip_bfloat16*)(ws + XG_OFF);

  // zero flags + both tagged h buffers (h0 = 0 with tag 0)
  (void)hipMemsetAsync(ws, 0, 266240, stream);

  xg_kernel<<<T_, 256, 0, stream>>>(x, emb, W_ih, xg);
  lstm_kernel<<<64, 512, 0, stream>>>(W_hh, b_ih, b_hh, W_fc, b_fc, xg,
                                      flags, hbuf2, hT, out);
}